// Round 13
// baseline (148.506 us; speedup 1.0000x reference)
//
#include <hip/hip_runtime.h>
#include <type_traits>

// MD-GRU (4-direction 2D GRU), block-resident wavefront scan, v13.
// = v12 plus ANTI-PHASE tile rotation: SIMD s hosts waves s and s+4
// (round-robin assignment); waves 0-3 run schedule M0 M1 E0 M2 E1 M3 E2 E3,
// waves 4-7 run M2 M3 E2 M0 E3 M1 E0 E1. The SIMD-mates are thus in
// opposite phases (one feeding the matrix pipe while the other issues
// epilogue VALU). v12 counters showed VALU (42%) and MFMA (32%) adding,
// not overlapping -> lockstep waves sat in identical phases.
// Workspace: [0,786432) U^T bf16 [a][n(384)][kk(256)]; then finals f32 [a][b][hh].

#define B_ 128
#define N_ 32
#define H_ 128
#define TH 384
#define KK 256

#define HBF_PLANE 4224   // 33 slots * 128 B (one 32-k plane)
#define HBF_BUF   16896  // 4 planes
#define XD_STEP   256    // 32 rows * float2

typedef short bf16x8 __attribute__((ext_vector_type(8)));
typedef float f32x4 __attribute__((ext_vector_type(4)));

__device__ inline ushort f2bf(float f) {  // round-to-nearest (ties away)
    return (ushort)((__float_as_uint(f) + 0x8000u) >> 16);
}
__device__ inline ushort f2bf_rne(float f) {
    unsigned u = __float_as_uint(f);
    return (ushort)((u + 0x7FFFu + ((u >> 16) & 1u)) >> 16);
}

#define NL2E -1.44269504088896f

// ---- U1,U2 (f32, [a][k][n]) -> U^T bf16 [a][n][kk], kk = mat*128 + k ----
__global__ void conv_u(const float* __restrict__ U1, const float* __restrict__ U2,
                       ushort* __restrict__ ubf) {
    __shared__ float t[32][33];
    int bx = blockIdx.x;
    int amat = bx / 48, tile = bx % 48;
    int kt = tile / 12, ntl = tile % 12;
    int a = amat >> 1, mat = amat & 1;
    int kk0 = kt * 32, n0 = ntl * 32;
    int tx = threadIdx.x, ty = threadIdx.y;
    const float* U = mat ? U2 : U1;
#pragma unroll
    for (int r = 0; r < 4; r++)
        t[ty + r * 8][tx] = U[(a * H_ + kk0 + ty + r * 8) * TH + n0 + tx];
    __syncthreads();
#pragma unroll
    for (int r = 0; r < 4; r++) {
        int n = n0 + ty + r * 8;
        int kkl = kk0 + tx;
        ubf[(a * TH + n) * KK + mat * H_ + kkl] = f2bf_rne(t[tx][ty + r * 8]);
    }
}

// ---- persistent block-resident scan: 256 blocks x 512 threads (8 waves) ----
__global__ __launch_bounds__(512, 2) void scan_all(
    const float* __restrict__ x, const float* __restrict__ Wx,
    const float* __restrict__ bvec, const ushort* __restrict__ ubf,
    float* __restrict__ finals) {

    __shared__ __align__(16) char hbf_c[2 * HBF_BUF];    // 33792 B
    __shared__ __align__(16) char xd_c[63 * XD_STEP];    // 16128 B

    int bx = blockIdx.x;
    int a = bx >> 6, chunk = bx & 63;
    int tid = threadIdx.x;
    int lane = tid & 63, wn = tid >> 6;  // wn in [0,8): 16 hh-cols x 3 gates
    int l16 = lane & 15, lg = lane >> 4;

    for (int idx = tid; idx < (2 * HBF_BUF) / 4; idx += 512) ((unsigned*)hbf_c)[idx] = 0u;
    for (int idx = tid; idx < (63 * XD_STEP) / 4; idx += 512) ((unsigned*)xd_c)[idx] = 0u;
    __syncthreads();

    // x -> diagonal-major LDS: xd[d][i] = {x_b0(i,d-i), x_b1(i,d-i)}
    const float* xg = x + (chunk * 2) * (N_ * N_);
    for (int cell = tid; cell < 1024; cell += 512) {
        int i = cell >> 5, j = cell & 31;
        int ri = (a & 1) ? (31 - i) : i;
        int cj = (a & 2) ? (31 - j) : j;
        float v0 = xg[ri * 32 + cj];
        float v1 = xg[1024 + ri * 32 + cj];
        *(float2*)(xd_c + (i + j) * XD_STEP + i * 8) = make_float2(v0, v1);
    }

    // persistent U^T fragments (96 regs; unified VGPR/AGPR file)
    const ushort* ub = ubf + a * (TH * KK);
    bf16x8 Bf[3][8];
#pragma unroll
    for (int p = 0; p < 3; p++) {
        int n = p * H_ + wn * 16 + l16;
#pragma unroll
        for (int ks = 0; ks < 8; ks++) {
            Bf[p][ks] = *(const bf16x8*)(ub + n * KK + ks * 32 + lg * 8);
            asm volatile("" : "+v"(Bf[p][ks]));
        }
    }

    int hh = wn * 16 + l16;
    float wxp[3], bsp[3];
    {
        float wr = Wx[a * TH + hh], br = bvec[a * TH + hh];
        float wz = Wx[a * TH + H_ + hh], bz = bvec[a * TH + H_ + hh];
        float wq = Wx[a * TH + 2 * H_ + hh], bq = bvec[a * TH + 2 * H_ + hh];
        wxp[0] = wr * NL2E; bsp[0] = br * NL2E;
        wxp[1] = wz * NL2E; bsp[1] = bz * NL2E;
        wxp[2] = wq;        bsp[2] = bq;
    }

    // loop-invariant LDS addresses (A-row m = mt*16+l16 -> cell m>>1, bl m&1)
    int ciA = l16 >> 1, blA = l16 & 1;
    int aT[4], aL[4], wb[4][2][2];
#pragma unroll
    for (int mt = 0; mt < 4; mt++) {
        int st = mt * 8 + ciA;  // top slot
        aT[mt] = st * 128 + ((blA * 64 + lg * 16) ^ ((st & 7) << 4));
        int sl = st + 1;        // left slot
        aL[mt] = sl * 128 + ((blA * 64 + lg * 16) ^ ((sl & 7) << 4));
#pragma unroll
        for (int p2 = 0; p2 < 2; p2++) {
            int sw = mt * 8 + lg * 2 + p2 + 1;  // write slot (row+1)
#pragma unroll
            for (int bl = 0; bl < 2; bl++)
                wb[mt][p2][bl] = (hh >> 5) * HBF_PLANE + sw * 128 +
                                 ((bl * 64 + (hh & 31) * 2) ^ ((sw & 7) << 4));
        }
    }

    const char* xdp = xd_c + lg * 16;
    __syncthreads();

    float hp[4][2][2];  // [mt][p2][bl] latest h of row mt*8+lg*2+p2
#pragma unroll
    for (int mt = 0; mt < 4; mt++)
#pragma unroll
        for (int p2 = 0; p2 < 2; p2++)
#pragma unroll
            for (int bl = 0; bl < 2; bl++) hp[mt][p2][bl] = 0.0f;

    int slsrc = (lane - 16) & 63;
    int sk = wn >> 2;  // 0: waves 0-3, 1: waves 4-7 (SIMD-mates differ)

    auto step = [&](int d, auto WRC) {
        constexpr int WRB = decltype(WRC)::value;
        constexpr int RDB = WRB ^ 1;
        const char* hbr = hbf_c + RDB * HBF_BUF;
        char* hbw = hbf_c + WRB * HBF_BUF;

        bool gm[4];
#pragma unroll
        for (int mt = 0; mt < 4; mt++)
            gm[mt] = (d >= mt * 8) && (d <= mt * 8 + 38);  // wave-uniform window

        f32x4 acc[4][3];
        f32x4 xv[4];
        float sh[4][2];
        const f32x4 z4 = {0.0f, 0.0f, 0.0f, 0.0f};

        auto do_mfma = [&](int mt) {
            bf16x8 af[8];
#pragma unroll
            for (int ks = 0; ks < 4; ks++) {
                af[ks] = *(const bf16x8*)(hbr + ks * HBF_PLANE + aT[mt]);
                af[ks + 4] = *(const bf16x8*)(hbr + ks * HBF_PLANE + aL[mt]);
            }
#pragma unroll
            for (int ks = 0; ks < 4; ks++)
#pragma unroll
                for (int p = 0; p < 3; p++)
                    acc[mt][p] = __builtin_amdgcn_mfma_f32_16x16x32_bf16(
                        af[ks], Bf[p][ks], (ks == 0) ? z4 : acc[mt][p], 0, 0, 0);
#pragma unroll
            for (int ks = 0; ks < 4; ks++)
#pragma unroll
                for (int p = 0; p < 3; p++)
                    acc[mt][p] = __builtin_amdgcn_mfma_f32_16x16x32_bf16(
                        af[ks + 4], Bf[p][ks + 4], acc[mt][p], 0, 0, 0);
        };

        auto do_aux = [&]() {  // shfl of prev-h + x loads (feeds epilogues)
#pragma unroll
            for (int mt = 0; mt < 4; mt++)
#pragma unroll
                for (int bl = 0; bl < 2; bl++)
                    sh[mt][bl] = __shfl(hp[mt][1][bl], slsrc, 64);
#pragma unroll
            for (int mt = 0; mt < 4; mt++)
                if (gm[mt]) xv[mt] = *(const f32x4*)(xdp + WRB * 256 + mt * 64);
        };

        auto do_epi = [&](int mt) {
            float hv[2][2];
#pragma unroll
            for (int p2 = 0; p2 < 2; p2++)
#pragma unroll
                for (int bl = 0; bl < 2; bl++) {
                    int r = p2 * 2 + bl;
                    float xb = xv[mt][r];
                    float htop = p2 ? hp[mt][0][bl]
                                    : (lg ? sh[mt][bl]
                                          : (mt ? sh[mt - 1][bl] : 0.0f));
                    float hlft = hp[mt][p2][bl];
                    float Gr = acc[mt][0][r];
                    float Gz = acc[mt][1][r];
                    float Gn = acc[mt][2][r];
                    float ar = __builtin_fmaf(Gr, NL2E, __builtin_fmaf(xb, wxp[0], bsp[0]));
                    float rg = __builtin_amdgcn_rcpf(1.0f + __builtin_amdgcn_exp2f(ar));
                    float az = __builtin_fmaf(Gz, NL2E, __builtin_fmaf(xb, wxp[1], bsp[1]));
                    float ez = __builtin_amdgcn_exp2f(az);
                    float vn = __builtin_fmaf(rg, Gn, __builtin_fmaf(xb, wxp[2], bsp[2]));
                    float en = __builtin_amdgcn_exp2f(vn * (2.0f * NL2E));
                    float pz = 1.0f + ez, pn = 1.0f + en;
                    float rp = __builtin_amdgcn_rcpf(pz * pn);
                    float zg = rp * pn;                       // sigmoid(z-arg)
                    float ng = __builtin_fmaf(2.0f * rp, pz, -1.0f);  // tanh(vn)
                    float hs = htop + hlft;
                    hv[p2][bl] = __builtin_fmaf(-zg, __builtin_fmaf(-0.5f, hs, ng), ng);
                }
#pragma unroll
            for (int p2 = 0; p2 < 2; p2++)
#pragma unroll
                for (int bl = 0; bl < 2; bl++) {
                    *(ushort*)(hbw + wb[mt][p2][bl]) = f2bf(hv[p2][bl]);
                    hp[mt][p2][bl] = hv[p2][bl];
                }
        };

        if (sk == 0) {
            // schedule A: M0 M1 [aux] E0 M2 E1 M3 E2 E3
            if (gm[0]) do_mfma(0);
            if (gm[1]) do_mfma(1);
            do_aux();
            if (gm[0]) do_epi(0);
            if (gm[2]) do_mfma(2);
            if (gm[1]) do_epi(1);
            if (gm[3]) do_mfma(3);
            if (gm[2]) do_epi(2);
            if (gm[3]) do_epi(3);
        } else {
            // schedule B (anti-phase): M2 M3 [aux] E2 M0 E3 M1 E0 E1
            if (gm[2]) do_mfma(2);
            if (gm[3]) do_mfma(3);
            do_aux();
            if (gm[2]) do_epi(2);
            if (gm[0]) do_mfma(0);
            if (gm[3]) do_epi(3);
            if (gm[1]) do_mfma(1);
            if (gm[0]) do_epi(0);
            if (gm[1]) do_epi(1);
        }

        __syncthreads();
    };

    for (int d = 0; d < 62; d += 2) {
        step(d, std::integral_constant<int, 0>{});
        step(d + 1, std::integral_constant<int, 1>{});
        xdp += 512;
    }
    step(62, std::integral_constant<int, 0>{});

    // terminal corner: row 31 = mt3/p2=1 on lg==3 lanes
    if (lg == 3) {
        finals[(a * B_ + chunk * 2) * H_ + hh] = hp[3][1][0];
        finals[(a * B_ + chunk * 2 + 1) * H_ + hh] = hp[3][1][1];
    }
}

// ---- final: concat 4 terminal h's -> logits -> log_softmax ----
__global__ void classify(const float* __restrict__ fin, const float* __restrict__ Wo,
                         const float* __restrict__ bo, float* __restrict__ out) {
    int b = blockIdx.x;
    int lane = threadIdx.x;  // 64
    float acc[10];
#pragma unroll
    for (int o = 0; o < 10; o++) acc[o] = 0.0f;
#pragma unroll
    for (int kkx = 0; kkx < 8; kkx++) {
        int k = kkx * 64 + lane;
        int a = k >> 7, hh = k & 127;
        float fh = fin[(a * B_ + b) * H_ + hh];
#pragma unroll
        for (int o = 0; o < 10; o++) acc[o] += fh * Wo[k * 10 + o];
    }
    float logits[10];
#pragma unroll
    for (int o = 0; o < 10; o++) {
        float v = acc[o];
#pragma unroll
        for (int off = 32; off; off >>= 1) v += __shfl_xor(v, off, 64);
        logits[o] = v + bo[o];
    }
    float m = logits[0];
#pragma unroll
    for (int o = 1; o < 10; o++) m = fmaxf(m, logits[o]);
    float s = 0.0f;
#pragma unroll
    for (int o = 0; o < 10; o++) s += __expf(logits[o] - m);
    float lse = m + __logf(s);
    if (lane == 0) {
#pragma unroll
        for (int o = 0; o < 10; o++) out[b * 10 + o] = logits[o] - lse;
    }
}

extern "C" void kernel_launch(void* const* d_in, const int* in_sizes, int n_in,
                              void* d_out, int out_size, void* d_ws, size_t ws_size,
                              hipStream_t stream) {
    const float* x = (const float*)d_in[0];
    const float* Wx = (const float*)d_in[1];
    const float* U1 = (const float*)d_in[2];
    const float* U2 = (const float*)d_in[3];
    const float* bv = (const float*)d_in[4];
    const float* Wo = (const float*)d_in[5];
    const float* bo = (const float*)d_in[6];
    float* out = (float*)d_out;

    char* ws = (char*)d_ws;
    ushort* ubf = (ushort*)ws;                // 786432 B
    float* finals = (float*)(ws + 786432);    // 4*128*128*4 = 256 KB

    hipLaunchKernelGGL(conv_u, dim3(384), dim3(32, 8), 0, stream, U1, U2, ubf);
    hipLaunchKernelGGL(scan_all, dim3(256), dim3(512), 0, stream, x, Wx, bv, ubf, finals);
    hipLaunchKernelGGL(classify, dim3(128), dim3(64), 0, stream, finals, Wo, bo, out);
}